// Round 1
// baseline (586.068 us; speedup 1.0000x reference)
//
#include <hip/hip_runtime.h>
#include <hip/hip_bf16.h>

// SNU network: 4 layers, B=256, T=100, N_IN=784, N_MID=1024, N_OUT=10, tau=0.8
// Strategy: layer-batched. Each layer = one big GEMM over M=B*T=25600 rows,
// then an elementwise recurrence over t (per (b,n) thread).

#define BDIM 256
#define TT   100
#define BB   256
#define MM   25600       // B*T
#define NMID 1024
#define K1   784
#define K1P  832         // 784 padded to 13*64
#define NOUT 10
#define L_TAU 0.8f

typedef __attribute__((ext_vector_type(8))) short short8;   // 8 bf16 (4 VGPRs)
typedef __attribute__((ext_vector_type(4))) float f32x4;

__device__ __forceinline__ void async_copy16(const void* g, void* l) {
    __builtin_amdgcn_global_load_lds(
        (const __attribute__((address_space(1))) unsigned int*)g,
        (__attribute__((address_space(3))) unsigned int*)l,
        16, 0, 0);
}

// ---- X f32 [M,784] -> bf16 [M,832] zero-padded -----------------------------
__global__ void convert_x(const float* __restrict__ X, __hip_bfloat16* __restrict__ XB) {
    int idx = blockIdx.x * BDIM + threadIdx.x;
    if (idx >= MM * K1P) return;
    int m = idx / K1P;
    int c = idx - m * K1P;
    float v = (c < K1) ? X[m * K1 + c] : 0.0f;
    XB[idx] = __float2bfloat16(v);
}

// ---- W f32 [K,N] -> WT bf16 [N,Kpad], zero-pad k>=K ------------------------
__global__ void transpose_convert(const float* __restrict__ W, __hip_bfloat16* __restrict__ WT,
                                  int K, int N, int Kpad) {
    __shared__ float tile[32][33];
    int k0 = blockIdx.x * 32;
    int n0 = blockIdx.y * 32;
    int tx = threadIdx.x & 31, ty = threadIdx.x >> 5;   // 256 threads: ty=0..7
    #pragma unroll
    for (int i = 0; i < 4; ++i) {
        int k = k0 + ty + i * 8;
        tile[ty + i * 8][tx] = (k < K) ? W[(long)k * N + n0 + tx] : 0.0f;
    }
    __syncthreads();
    #pragma unroll
    for (int i = 0; i < 4; ++i) {
        int n = n0 + ty + i * 8;
        WT[(long)n * Kpad + k0 + tx] = __float2bfloat16(tile[tx][ty + i * 8]);
    }
}

// ---- GEMM: C[M,N] = A[M,K] * BT[N,K]^T (bf16 in, f32 out) ------------------
// 128x128 block tile, BK=64, 4 waves of 64x64, 16x16x32 bf16 MFMA, 4x4 frags.
#define BM 128
#define BN 128
#define BK 64
__global__ __launch_bounds__(256) void gemm_bt(
    const __hip_bfloat16* __restrict__ A,   // [M,K]
    const __hip_bfloat16* __restrict__ BT,  // [N,K]
    float* __restrict__ C,                  // [M,N]
    int M, int N, int K)
{
    __shared__ __hip_bfloat16 As[BM * BK];  // [row][k], row stride 64
    __shared__ __hip_bfloat16 Bs[BN * BK];

    const int tid  = threadIdx.x;
    const int wave = tid >> 6;
    const int lane = tid & 63;
    const int bm = blockIdx.y * BM;
    const int bn = blockIdx.x * BN;
    const int wr = (wave >> 1) * 64;
    const int wc = (wave & 1) * 64;

    f32x4 acc[4][4] = {};

    // staging map: thread -> (row = tid>>3, col8 = (tid&7)*8); LDS offset == tid*16B
    const int srow = tid >> 3;
    const int scol = (tid & 7) * 8;
    const __hip_bfloat16* Aptr = A  + (long)(bm + srow) * K + scol;
    const __hip_bfloat16* Bptr = BT + (long)(bn + srow) * K + scol;

    for (int k0 = 0; k0 < K; k0 += BK) {
        #pragma unroll
        for (int i = 0; i < 4; ++i) {
            async_copy16(Aptr + (long)(i * 32) * K + k0, &As[(srow + i * 32) * BK + scol]);
            async_copy16(Bptr + (long)(i * 32) * K + k0, &Bs[(srow + i * 32) * BK + scol]);
        }
        __syncthreads();   // compiler emits s_waitcnt vmcnt(0) before s_barrier

        #pragma unroll
        for (int kk = 0; kk < BK; kk += 32) {
            const int mrow = lane & 15;
            const int krow = kk + (lane >> 4) * 8;
            short8 af[4], bfr[4];
            #pragma unroll
            for (int i = 0; i < 4; ++i)
                af[i] = *(const short8*)&As[(wr + i * 16 + mrow) * BK + krow];
            #pragma unroll
            for (int i = 0; i < 4; ++i)
                bfr[i] = *(const short8*)&Bs[(wc + i * 16 + mrow) * BK + krow];
            #pragma unroll
            for (int i = 0; i < 4; ++i)
                #pragma unroll
                for (int j = 0; j < 4; ++j)
                    acc[i][j] = __builtin_amdgcn_mfma_f32_16x16x32_bf16(af[i], bfr[j], acc[i][j], 0, 0, 0);
        }
        __syncthreads();
    }

    // epilogue: C/D layout col=lane&15, row=(lane>>4)*4+reg
    const int col  = lane & 15;
    const int row4 = (lane >> 4) * 4;
    #pragma unroll
    for (int i = 0; i < 4; ++i)
        #pragma unroll
        for (int j = 0; j < 4; ++j)
            #pragma unroll
            for (int r = 0; r < 4; ++r) {
                int gr = bm + wr + i * 16 + row4 + r;
                int gc = bn + wc + j * 16 + col;
                C[(long)gr * N + gc] = acc[i][j][r];
            }
}

// ---- SNU recurrence for N_MID layers: read Z f32, write Y bf16 -------------
__global__ void snu_recur(const float* __restrict__ Z, const float* __restrict__ bias,
                          __hip_bfloat16* __restrict__ Y) {
    int idx = blockIdx.x * BDIM + threadIdx.x;   // b*1024 + n, total 262144
    int n = idx & (NMID - 1);
    int b = idx >> 10;
    float bv = bias[n];
    float s = 0.0f, y = 0.0f;
    const float* zp = Z + (long)b * TT * NMID + n;
    __hip_bfloat16* yp = Y + (long)b * TT * NMID + n;
    for (int t = 0; t < TT; ++t) {
        float z = zp[(long)t * NMID];
        s = fmaxf(fmaf(L_TAU * s, 1.0f - y, z), 0.0f);
        y = 1.0f / (1.0f + __expf(-(s + bv)));
        yp[(long)t * NMID] = __float2bfloat16(y);
    }
}

// ---- Layer 4 GEMM: Z4[M,10] = Y3[M,1024] * W4[1024,10] ---------------------
// one wave per row; W4 staged transposed [n][k] in LDS (conflict-free: bank=k%32)
__global__ __launch_bounds__(256) void layer4_gemm(const __hip_bfloat16* __restrict__ Y3,
                                                   const float* __restrict__ W4,
                                                   float* __restrict__ Z4) {
    __shared__ float w4t[NOUT][NMID];   // 40 KB
    int tid = threadIdx.x;
    for (int i = tid; i < NOUT * NMID; i += BDIM) {
        int n = i >> 10;
        int k = i & (NMID - 1);
        w4t[n][k] = W4[k * NOUT + n];
    }
    __syncthreads();
    int wave = tid >> 6, lane = tid & 63;
    int m = blockIdx.x * 4 + wave;
    const __hip_bfloat16* yrow = Y3 + (long)m * NMID;
    float yv[16];
    #pragma unroll
    for (int j = 0; j < 16; ++j)
        yv[j] = __bfloat162float(yrow[j * 64 + lane]);   // coalesced u16 loads
    float res = 0.0f;
    #pragma unroll
    for (int n = 0; n < NOUT; ++n) {
        float a = 0.0f;
        #pragma unroll
        for (int j = 0; j < 16; ++j)
            a = fmaf(yv[j], w4t[n][j * 64 + lane], a);
        #pragma unroll
        for (int off = 32; off; off >>= 1)
            a += __shfl_xor(a, off);
        if (lane == n) res = a;
    }
    if (lane < NOUT) Z4[m * NOUT + lane] = res;
}

// ---- Layer 4 recurrence + m accumulation -----------------------------------
__global__ void snu4_recur(const float* __restrict__ Z4, const float* __restrict__ b4,
                           float* __restrict__ m_out) {
    int idx = blockIdx.x * BDIM + threadIdx.x;   // b*10+n, total 2560
    if (idx >= BB * NOUT) return;
    int n = idx % NOUT, b = idx / NOUT;
    float bv = b4[n];
    float s = 0.0f, y = 0.0f, msum = 0.0f;
    const float* zp = Z4 + (long)b * TT * NOUT + n;
    for (int t = 0; t < TT; ++t) {
        float z = zp[t * NOUT];
        s = fmaxf(fmaf(L_TAU * s, 1.0f - y, z), 0.0f);
        y = 1.0f / (1.0f + __expf(-(s + bv)));
        msum += y;
    }
    m_out[b * NOUT + n] = msum;
}

// ---- loss = -mean_b log_softmax(m)[b, y[b]] --------------------------------
__global__ void loss_kernel(const float* __restrict__ m, const int* __restrict__ y,
                            float* __restrict__ out) {
    __shared__ float red[BDIM];
    int b = threadIdx.x;   // 256 threads, 1 block
    float v[NOUT];
    float mx = -1e30f;
    #pragma unroll
    for (int n = 0; n < NOUT; ++n) { v[n] = m[b * NOUT + n]; mx = fmaxf(mx, v[n]); }
    float se = 0.0f;
    #pragma unroll
    for (int n = 0; n < NOUT; ++n) se += __expf(v[n] - mx);
    float lse = mx + __logf(se);
    int lbl = y[b];
    float vy = 0.0f;
    #pragma unroll
    for (int n = 0; n < NOUT; ++n) if (n == lbl) vy = v[n];
    red[b] = -(vy - lse);
    __syncthreads();
    for (int off = 128; off; off >>= 1) {
        if (b < off) red[b] += red[b + off];
        __syncthreads();
    }
    if (b == 0) out[0] = red[0] / (float)BB;
}

extern "C" void kernel_launch(void* const* d_in, const int* in_sizes, int n_in,
                              void* d_out, int out_size, void* d_ws, size_t ws_size,
                              hipStream_t stream) {
    const float* x  = (const float*)d_in[0];
    const int*   y  = (const int*)  d_in[1];
    const float* W1 = (const float*)d_in[2];
    const float* b1 = (const float*)d_in[3];
    const float* W2 = (const float*)d_in[4];
    const float* b2 = (const float*)d_in[5];
    const float* W3 = (const float*)d_in[6];
    const float* b3 = (const float*)d_in[7];
    const float* W4 = (const float*)d_in[8];
    const float* b4 = (const float*)d_in[9];
    float* out = (float*)d_out;

    char* ws = (char*)d_ws;
    size_t off = 0;
    auto alloc = [&](size_t bytes) {
        char* p = ws + off;
        off = (off + bytes + 255) & ~(size_t)255;
        return (void*)p;
    };
    __hip_bfloat16* XB  = (__hip_bfloat16*)alloc((size_t)MM * K1P * 2);
    __hip_bfloat16* W1T = (__hip_bfloat16*)alloc((size_t)NMID * K1P * 2);
    __hip_bfloat16* W2T = (__hip_bfloat16*)alloc((size_t)NMID * NMID * 2);
    __hip_bfloat16* W3T = (__hip_bfloat16*)alloc((size_t)NMID * NMID * 2);
    float*          Z   = (float*)         alloc((size_t)MM * NMID * 4);
    __hip_bfloat16* Ya  = (__hip_bfloat16*)alloc((size_t)MM * NMID * 2);
    __hip_bfloat16* Yb  = (__hip_bfloat16*)alloc((size_t)MM * NMID * 2);
    float*          Z4  = (float*)         alloc((size_t)MM * NOUT * 4);

    // prep: convert x, transpose+convert weights
    convert_x<<<(MM * K1P + BDIM - 1) / BDIM, BDIM, 0, stream>>>(x, XB);
    transpose_convert<<<dim3(K1P / 32, NMID / 32), BDIM, 0, stream>>>(W1, W1T, K1, NMID, K1P);
    transpose_convert<<<dim3(NMID / 32, NMID / 32), BDIM, 0, stream>>>(W2, W2T, NMID, NMID, NMID);
    transpose_convert<<<dim3(NMID / 32, NMID / 32), BDIM, 0, stream>>>(W3, W3T, NMID, NMID, NMID);

    // layer 1
    gemm_bt<<<dim3(NMID / BN, MM / BM), BDIM, 0, stream>>>(XB, W1T, Z, MM, NMID, K1P);
    snu_recur<<<(BB * NMID) / BDIM, BDIM, 0, stream>>>(Z, b1, Ya);
    // layer 2
    gemm_bt<<<dim3(NMID / BN, MM / BM), BDIM, 0, stream>>>(Ya, W2T, Z, MM, NMID, NMID);
    snu_recur<<<(BB * NMID) / BDIM, BDIM, 0, stream>>>(Z, b2, Yb);
    // layer 3 (reuse Ya)
    gemm_bt<<<dim3(NMID / BN, MM / BM), BDIM, 0, stream>>>(Yb, W3T, Z, MM, NMID, NMID);
    snu_recur<<<(BB * NMID) / BDIM, BDIM, 0, stream>>>(Z, b3, Ya);
    // layer 4
    layer4_gemm<<<MM / 4, BDIM, 0, stream>>>(Ya, W4, Z4);
    snu4_recur<<<(BB * NOUT + BDIM - 1) / BDIM, BDIM, 0, stream>>>(Z4, b4, out + 1);
    loss_kernel<<<1, BDIM, 0, stream>>>(out + 1, y, out);
}

// Round 2
// 579.788 us; speedup vs baseline: 1.0108x; 1.0108x over previous
//
#include <hip/hip_runtime.h>
#include <hip/hip_bf16.h>

// SNU network: 4 layers, B=256, T=100, N_IN=784, N_MID=1024, N_OUT=10, tau=0.8
// Layer-batched: per layer one big GEMM over M=B*T=25600 rows, then an
// elementwise recurrence over t. GEMM writes bf16 Z^T [N][M] so the
// recurrence reads contiguous-in-t and the epilogue packs 4 rows/store.

#define BDIM 256
#define TT   100
#define BB   256
#define MM   25600       // B*T
#define NMID 1024
#define K1   784
#define K1P  832         // 784 padded to 13*64
#define NOUT 10
#define L_TAU 0.8f

typedef __attribute__((ext_vector_type(8))) short short8;   // 8 bf16 (4 VGPRs)
typedef __attribute__((ext_vector_type(4))) float f32x4;

__device__ __forceinline__ void async_copy16(const void* g, void* l) {
    __builtin_amdgcn_global_load_lds(
        (const __attribute__((address_space(1))) unsigned int*)g,
        (__attribute__((address_space(3))) unsigned int*)l,
        16, 0, 0);
}

__device__ __forceinline__ unsigned short f2bf(float f) {
    __hip_bfloat16 h = __float2bfloat16(f);
    return __builtin_bit_cast(unsigned short, h);
}
__device__ __forceinline__ float bf2f(unsigned short u) {
    return __uint_as_float((unsigned)u << 16);
}

// ---- X f32 [M,784] -> bf16 [M,832] zero-padded; one block per row ----------
__global__ void convert_x(const float* __restrict__ X, __hip_bfloat16* __restrict__ XB) {
    int row = blockIdx.x;
    int t = threadIdx.x;
    if (t >= K1P / 4) return;                 // 208 active threads
    ushort4 pk = {0, 0, 0, 0};
    if (t < K1 / 4) {                         // 196: covers cols 0..783 exactly
        float4 v = *(const float4*)(X + (long)row * K1 + t * 4);
        pk.x = f2bf(v.x); pk.y = f2bf(v.y); pk.z = f2bf(v.z); pk.w = f2bf(v.w);
    }
    *(ushort4*)(XB + (long)row * K1P + t * 4) = pk;
}

// ---- W f32 [K,N] -> WT bf16 [N,Kpad], zero-pad k>=K ------------------------
__global__ void transpose_convert(const float* __restrict__ W, __hip_bfloat16* __restrict__ WT,
                                  int K, int N, int Kpad) {
    __shared__ float tile[32][33];
    int k0 = blockIdx.x * 32;
    int n0 = blockIdx.y * 32;
    int tx = threadIdx.x & 31, ty = threadIdx.x >> 5;   // 256 threads: ty=0..7
    #pragma unroll
    for (int i = 0; i < 4; ++i) {
        int k = k0 + ty + i * 8;
        tile[ty + i * 8][tx] = (k < K) ? W[(long)k * N + n0 + tx] : 0.0f;
    }
    __syncthreads();
    #pragma unroll
    for (int i = 0; i < 4; ++i) {
        int n = n0 + ty + i * 8;
        WT[(long)n * Kpad + k0 + tx] = __float2bfloat16(tile[tx][ty + i * 8]);
    }
}

// ---- GEMM: CT[N,M] = (A[M,K] * BT[N,K]^T)^T, bf16 in, bf16 out -------------
// 128x128 block tile, BK=64, 4 waves of 64x64, 16x16x32 bf16 MFMA, 4x4 frags.
// LDS chunk-XOR swizzle (conflict-free b128 reads); XCD-aware block swizzle
// so the 8 N-blocks sharing an A strip land on one XCD (L2 A-reuse).
#define BM 128
#define BN 128
#define BK 64
#define MSTRIPS (MM / BM)        // 200
#define NSTRIPS (NMID / BN)      // 8
__global__ __launch_bounds__(256) void gemm_bt(
    const __hip_bfloat16* __restrict__ A,   // [M,K]
    const __hip_bfloat16* __restrict__ BT,  // [N,K]
    __hip_bfloat16* __restrict__ CT,        // [N,M]  (C transposed)
    int K)
{
    __shared__ __hip_bfloat16 As[BM * BK];  // slot (row,c) holds global chunk c^(row&7)
    __shared__ __hip_bfloat16 Bs[BN * BK];

    const int tid  = threadIdx.x;
    const int wave = tid >> 6;
    const int lane = tid & 63;

    // XCD swizzle: consecutive blockIdx round-robin across 8 XCDs; give each
    // XCD 25 whole M-strips so all 8 N-blocks of a strip share that XCD's L2.
    const int l    = blockIdx.x;
    const int xcd  = l & 7;
    const int p    = l >> 3;                 // 0..199 within XCD
    const int bm   = (xcd * (MSTRIPS / 8) + (p >> 3)) * BM;
    const int bn   = (p & 7) * BN;

    const int wr = (wave >> 1) * 64;
    const int wc = (wave & 1) * 64;

    f32x4 acc[4][4] = {};

    // staging: LDS dest is lane-linear (tid*16B); global source column is
    // chunk-XOR-swizzled by row&7 (invariant under +32 row steps).
    const int srow  = tid >> 3;
    const int lcol  = (tid & 7) * 8;                       // LDS chunk (linear)
    const int gcol  = ((tid & 7) ^ (srow & 7)) * 8;        // global chunk (swizzled)
    const __hip_bfloat16* Aptr = A  + (long)(bm + srow) * K + gcol;
    const __hip_bfloat16* Bptr = BT + (long)(bn + srow) * K + gcol;

    for (int k0 = 0; k0 < K; k0 += BK) {
        #pragma unroll
        for (int i = 0; i < 4; ++i) {
            async_copy16(Aptr + (long)(i * 32) * K + k0, &As[(srow + i * 32) * BK + lcol]);
            async_copy16(Bptr + (long)(i * 32) * K + k0, &Bs[(srow + i * 32) * BK + lcol]);
        }
        __syncthreads();

        const int mrow = lane & 15;
        const int qoff = lane >> 4;      // which 8-elem chunk within 32-K slab
        const int sxor = lane & 7;       // row&7 for all this lane's frag rows
        #pragma unroll
        for (int kk = 0; kk < BK; kk += 32) {
            const int sc = (((kk >> 3) + qoff) ^ sxor) * 8;   // swizzled LDS col
            short8 af[4], bfr[4];
            #pragma unroll
            for (int i = 0; i < 4; ++i)
                af[i] = *(const short8*)&As[(wr + i * 16 + mrow) * BK + sc];
            #pragma unroll
            for (int i = 0; i < 4; ++i)
                bfr[i] = *(const short8*)&Bs[(wc + i * 16 + mrow) * BK + sc];
            #pragma unroll
            for (int i = 0; i < 4; ++i)
                #pragma unroll
                for (int j = 0; j < 4; ++j)
                    acc[i][j] = __builtin_amdgcn_mfma_f32_16x16x32_bf16(af[i], bfr[j], acc[i][j], 0, 0, 0);
        }
        __syncthreads();
    }

    // epilogue: C/D layout col=lane&15, row=(lane>>4)*4+reg. In C^T the 4
    // accumulator rows are contiguous -> one 8B packed store per fragment.
    const int col  = lane & 15;
    const int row4 = (lane >> 4) * 4;
    #pragma unroll
    for (int j = 0; j < 4; ++j)
        #pragma unroll
        for (int i = 0; i < 4; ++i) {
            int gr = bm + wr + i * 16 + row4;
            int gc = bn + wc + j * 16 + col;
            ushort4 pk;
            pk.x = f2bf(acc[i][j][0]);
            pk.y = f2bf(acc[i][j][1]);
            pk.z = f2bf(acc[i][j][2]);
            pk.w = f2bf(acc[i][j][3]);
            *(ushort4*)&CT[(long)gc * MM + gr] = pk;
        }
}

// ---- SNU recurrence: read Z^T bf16 [N][M] (contiguous in t), write Y [M][N] -
__global__ void snu_recur(const __hip_bfloat16* __restrict__ ZT,
                          const float* __restrict__ bias,
                          __hip_bfloat16* __restrict__ Y) {
    int idx = blockIdx.x * BDIM + threadIdx.x;   // b*1024 + n
    int n = idx & (NMID - 1);
    int b = idx >> 10;
    float bv = bias[n];
    float s = 0.0f, y = 0.0f;
    const __hip_bfloat16* zp = ZT + (long)n * MM + b * TT;  // byte offset %8==0
    __hip_bfloat16* yp = Y + (long)b * TT * NMID + n;
    for (int t0 = 0; t0 < TT; t0 += 4) {
        ushort4 z4 = *(const ushort4*)(zp + t0);
        unsigned short zz[4] = {z4.x, z4.y, z4.z, z4.w};
        #pragma unroll
        for (int j = 0; j < 4; ++j) {
            float z = bf2f(zz[j]);
            s = fmaxf(fmaf(L_TAU * s, 1.0f - y, z), 0.0f);
            y = 1.0f / (1.0f + __expf(-(s + bv)));
            yp[(long)(t0 + j) * NMID] = __float2bfloat16(y);
        }
    }
}

// ---- Layer 4 GEMM: Z4[M,10] = Y3[M,1024] * W4[1024,10] ---------------------
// 64 rows per block (amortize 40KB W4 staging); one wave handles 16 rows.
__global__ __launch_bounds__(256) void layer4_gemm(const __hip_bfloat16* __restrict__ Y3,
                                                   const float* __restrict__ W4,
                                                   float* __restrict__ Z4) {
    __shared__ float w4t[NOUT][NMID];   // 40 KB
    int tid = threadIdx.x;
    for (int i = tid; i < NOUT * NMID; i += BDIM) {
        int n = i >> 10;
        int k = i & (NMID - 1);
        w4t[n][k] = W4[k * NOUT + n];
    }
    __syncthreads();
    int wave = tid >> 6, lane = tid & 63;
    for (int rr = 0; rr < 16; ++rr) {
        int m = blockIdx.x * 64 + wave * 16 + rr;
        const __hip_bfloat16* yrow = Y3 + (long)m * NMID;
        float yv[16];
        #pragma unroll
        for (int j = 0; j < 16; ++j)
            yv[j] = __bfloat162float(yrow[j * 64 + lane]);
        float res = 0.0f;
        #pragma unroll
        for (int n = 0; n < NOUT; ++n) {
            float a = 0.0f;
            #pragma unroll
            for (int j = 0; j < 16; ++j)
                a = fmaf(yv[j], w4t[n][j * 64 + lane], a);
            #pragma unroll
            for (int off = 32; off; off >>= 1)
                a += __shfl_xor(a, off);
            if (lane == n) res = a;
        }
        if (lane < NOUT) Z4[(long)m * NOUT + lane] = res;
    }
}

// ---- Layer 4 recurrence + m accumulation -----------------------------------
__global__ void snu4_recur(const float* __restrict__ Z4, const float* __restrict__ b4,
                           float* __restrict__ m_out) {
    int idx = blockIdx.x * BDIM + threadIdx.x;   // b*10+n
    if (idx >= BB * NOUT) return;
    int n = idx % NOUT, b = idx / NOUT;
    float bv = b4[n];
    float s = 0.0f, y = 0.0f, msum = 0.0f;
    const float* zp = Z4 + (long)b * TT * NOUT + n;
    for (int t = 0; t < TT; ++t) {
        float z = zp[t * NOUT];
        s = fmaxf(fmaf(L_TAU * s, 1.0f - y, z), 0.0f);
        y = 1.0f / (1.0f + __expf(-(s + bv)));
        msum += y;
    }
    m_out[b * NOUT + n] = msum;
}

// ---- loss = -mean_b log_softmax(m)[b, y[b]] --------------------------------
__global__ void loss_kernel(const float* __restrict__ m, const int* __restrict__ y,
                            float* __restrict__ out) {
    __shared__ float red[BDIM];
    int b = threadIdx.x;   // 256 threads, 1 block
    float v[NOUT];
    float mx = -1e30f;
    #pragma unroll
    for (int n = 0; n < NOUT; ++n) { v[n] = m[b * NOUT + n]; mx = fmaxf(mx, v[n]); }
    float se = 0.0f;
    #pragma unroll
    for (int n = 0; n < NOUT; ++n) se += __expf(v[n] - mx);
    float lse = mx + __logf(se);
    int lbl = y[b];
    float vy = 0.0f;
    #pragma unroll
    for (int n = 0; n < NOUT; ++n) if (n == lbl) vy = v[n];
    red[b] = -(vy - lse);
    __syncthreads();
    for (int off = 128; off; off >>= 1) {
        if (b < off) red[b] += red[b + off];
        __syncthreads();
    }
    if (b == 0) out[0] = red[0] / (float)BB;
}

extern "C" void kernel_launch(void* const* d_in, const int* in_sizes, int n_in,
                              void* d_out, int out_size, void* d_ws, size_t ws_size,
                              hipStream_t stream) {
    const float* x  = (const float*)d_in[0];
    const int*   y  = (const int*)  d_in[1];
    const float* W1 = (const float*)d_in[2];
    const float* b1 = (const float*)d_in[3];
    const float* W2 = (const float*)d_in[4];
    const float* b2 = (const float*)d_in[5];
    const float* W3 = (const float*)d_in[6];
    const float* b3 = (const float*)d_in[7];
    const float* W4 = (const float*)d_in[8];
    const float* b4 = (const float*)d_in[9];
    float* out = (float*)d_out;

    char* ws = (char*)d_ws;
    size_t off = 0;
    auto alloc = [&](size_t bytes) {
        char* p = ws + off;
        off = (off + bytes + 255) & ~(size_t)255;
        return (void*)p;
    };
    __hip_bfloat16* XB  = (__hip_bfloat16*)alloc((size_t)MM * K1P * 2);
    __hip_bfloat16* W1T = (__hip_bfloat16*)alloc((size_t)NMID * K1P * 2);
    __hip_bfloat16* W2T = (__hip_bfloat16*)alloc((size_t)NMID * NMID * 2);
    __hip_bfloat16* W3T = (__hip_bfloat16*)alloc((size_t)NMID * NMID * 2);
    __hip_bfloat16* ZT  = (__hip_bfloat16*)alloc((size_t)NMID * MM * 2);  // Z^T [N][M]
    __hip_bfloat16* Ya  = (__hip_bfloat16*)alloc((size_t)MM * NMID * 2);
    __hip_bfloat16* Yb  = (__hip_bfloat16*)alloc((size_t)MM * NMID * 2);
    float*          Z4  = (float*)         alloc((size_t)MM * NOUT * 4);

    // prep: convert x, transpose+convert weights
    convert_x<<<MM, BDIM, 0, stream>>>(x, XB);
    transpose_convert<<<dim3(K1P / 32, NMID / 32), BDIM, 0, stream>>>(W1, W1T, K1, NMID, K1P);
    transpose_convert<<<dim3(NMID / 32, NMID / 32), BDIM, 0, stream>>>(W2, W2T, NMID, NMID, NMID);
    transpose_convert<<<dim3(NMID / 32, NMID / 32), BDIM, 0, stream>>>(W3, W3T, NMID, NMID, NMID);

    const int gblocks = MSTRIPS * NSTRIPS;   // 1600
    // layer 1
    gemm_bt<<<gblocks, BDIM, 0, stream>>>(XB, W1T, ZT, K1P);
    snu_recur<<<(BB * NMID) / BDIM, BDIM, 0, stream>>>(ZT, b1, Ya);
    // layer 2
    gemm_bt<<<gblocks, BDIM, 0, stream>>>(Ya, W2T, ZT, NMID);
    snu_recur<<<(BB * NMID) / BDIM, BDIM, 0, stream>>>(ZT, b2, Yb);
    // layer 3 (reuse Ya)
    gemm_bt<<<gblocks, BDIM, 0, stream>>>(Yb, W3T, ZT, NMID);
    snu_recur<<<(BB * NMID) / BDIM, BDIM, 0, stream>>>(ZT, b3, Ya);
    // layer 4
    layer4_gemm<<<MM / 64, BDIM, 0, stream>>>(Ya, W4, Z4);
    snu4_recur<<<(BB * NOUT + BDIM - 1) / BDIM, BDIM, 0, stream>>>(Z4, b4, out + 1);
    loss_kernel<<<1, BDIM, 0, stream>>>(out + 1, y, out);
}

// Round 3
// 498.343 us; speedup vs baseline: 1.1760x; 1.1634x over previous
//
#include <hip/hip_runtime.h>
#include <hip/hip_bf16.h>

// SNU network: 4 layers, B=256, T=100, N_IN=784, N_MID=1024, N_OUT=10, tau=0.8
// Layer-batched, activations in [T][B][N] row order (m = t*B + b) so the
// per-(b,n) time recurrences read/write fully coalesced. GEMM uses swapped
// MFMA operands so the accumulator's register dim is n -> packed ushort4
// stores into normal [M][N] layout.

#define BDIM 256
#define TT   100
#define BB   256
#define MM   25600       // B*T
#define NMID 1024
#define K1   784
#define K1P  832         // 784 padded to 13*64
#define NOUT 10
#define L_TAU 0.8f

typedef __attribute__((ext_vector_type(8))) short short8;   // 8 bf16 (4 VGPRs)
typedef __attribute__((ext_vector_type(4))) float f32x4;

__device__ __forceinline__ void async_copy16(const void* g, void* l) {
    __builtin_amdgcn_global_load_lds(
        (const __attribute__((address_space(1))) unsigned int*)g,
        (__attribute__((address_space(3))) unsigned int*)l,
        16, 0, 0);
}

__device__ __forceinline__ unsigned short f2bf(float f) {
    __hip_bfloat16 h = __float2bfloat16(f);
    return __builtin_bit_cast(unsigned short, h);
}
__device__ __forceinline__ float bf2f(unsigned short u) {
    return __uint_as_float((unsigned)u << 16);
}

// ---- X f32 [B][T][784] -> bf16 [m=t*B+b][832] zero-padded ------------------
__global__ void convert_x(const float* __restrict__ X, __hip_bfloat16* __restrict__ XB) {
    int m = blockIdx.x;                  // t*BB + b
    int b = m & (BB - 1);
    int t = m >> 8;
    int th = threadIdx.x;
    if (th >= K1P / 4) return;           // 208 active threads
    ushort4 pk = {0, 0, 0, 0};
    if (th < K1 / 4) {                   // 196 threads cover cols 0..783
        float4 v = *(const float4*)(X + ((long)b * TT + t) * K1 + th * 4);
        pk.x = f2bf(v.x); pk.y = f2bf(v.y); pk.z = f2bf(v.z); pk.w = f2bf(v.w);
    }
    *(ushort4*)(XB + (long)m * K1P + th * 4) = pk;
}

// ---- W f32 [K,N] -> WT bf16 [N,Kpad], zero-pad k>=K ------------------------
__global__ void transpose_convert(const float* __restrict__ W, __hip_bfloat16* __restrict__ WT,
                                  int K, int N, int Kpad) {
    __shared__ float tile[32][33];
    int k0 = blockIdx.x * 32;
    int n0 = blockIdx.y * 32;
    int tx = threadIdx.x & 31, ty = threadIdx.x >> 5;   // 256 threads: ty=0..7
    #pragma unroll
    for (int i = 0; i < 4; ++i) {
        int k = k0 + ty + i * 8;
        tile[ty + i * 8][tx] = (k < K) ? W[(long)k * N + n0 + tx] : 0.0f;
    }
    __syncthreads();
    #pragma unroll
    for (int i = 0; i < 4; ++i) {
        int n = n0 + ty + i * 8;
        WT[(long)n * Kpad + k0 + tx] = __float2bfloat16(tile[tx][ty + i * 8]);
    }
}

// ---- GEMM: C[M,N] = A[M,K] * BT[N,K]^T, bf16 in, bf16 out ------------------
// 128x128 block tile, BK=64, 4 waves of 64x64, 16x16x32 bf16 MFMA, 4x4 frags.
// mfma(bfr, af): D reg-dim = n, lane-dim = m -> ushort4 stores along n.
// LDS chunk-XOR swizzle (conflict-free b128); XCD-aware block swizzle.
#define BM 128
#define BN 128
#define BK 64
#define MSTRIPS (MM / BM)        // 200
#define NSTRIPS (NMID / BN)      // 8
__global__ __launch_bounds__(256) void gemm_bt(
    const __hip_bfloat16* __restrict__ A,   // [M,K]
    const __hip_bfloat16* __restrict__ BT,  // [N,K]
    __hip_bfloat16* __restrict__ C,         // [M,N]
    int K)
{
    __shared__ __hip_bfloat16 As[BM * BK];  // slot (row,c) holds global chunk c^(row&7)
    __shared__ __hip_bfloat16 Bs[BN * BK];

    const int tid  = threadIdx.x;
    const int wave = tid >> 6;
    const int lane = tid & 63;

    // XCD swizzle: give each XCD whole M-strips so all 8 N-blocks of a strip
    // share that XCD's L2 copy of the A strip.
    const int l    = blockIdx.x;
    const int xcd  = l & 7;
    const int p    = l >> 3;                 // 0..199 within XCD
    const int bm   = (xcd * (MSTRIPS / 8) + (p >> 3)) * BM;
    const int bn   = (p & 7) * BN;

    const int wr = (wave >> 1) * 64;
    const int wc = (wave & 1) * 64;

    f32x4 acc[4][4] = {};

    // staging: LDS dest lane-linear (tid*16B); global column chunk-XOR swizzled
    const int srow  = tid >> 3;
    const int lcol  = (tid & 7) * 8;                       // LDS chunk (linear)
    const int gcol  = ((tid & 7) ^ (srow & 7)) * 8;        // global chunk (swizzled)
    const __hip_bfloat16* Aptr = A  + (long)(bm + srow) * K + gcol;
    const __hip_bfloat16* Bptr = BT + (long)(bn + srow) * K + gcol;

    for (int k0 = 0; k0 < K; k0 += BK) {
        #pragma unroll
        for (int i = 0; i < 4; ++i) {
            async_copy16(Aptr + (long)(i * 32) * K + k0, &As[(srow + i * 32) * BK + lcol]);
            async_copy16(Bptr + (long)(i * 32) * K + k0, &Bs[(srow + i * 32) * BK + lcol]);
        }
        __syncthreads();

        const int mrow = lane & 15;
        const int qoff = lane >> 4;      // which 8-elem chunk within 32-K slab
        const int sxor = lane & 7;
        #pragma unroll
        for (int kk = 0; kk < BK; kk += 32) {
            const int sc = (((kk >> 3) + qoff) ^ sxor) * 8;   // swizzled LDS col
            short8 af[4], bfr[4];
            #pragma unroll
            for (int i = 0; i < 4; ++i)
                af[i] = *(const short8*)&As[(wr + i * 16 + mrow) * BK + sc];
            #pragma unroll
            for (int i = 0; i < 4; ++i)
                bfr[i] = *(const short8*)&Bs[(wc + i * 16 + mrow) * BK + sc];
            #pragma unroll
            for (int i = 0; i < 4; ++i)
                #pragma unroll
                for (int j = 0; j < 4; ++j)
                    acc[i][j] = __builtin_amdgcn_mfma_f32_16x16x32_bf16(bfr[j], af[i], acc[i][j], 0, 0, 0);
        }
        __syncthreads();
    }

    // epilogue: D[n-dim in regs][m-dim in lanes]: col=lane&15 -> m, reg -> n.
    // Each fragment: 4 consecutive n at fixed m -> one 8B packed store.
    const int mcol  = lane & 15;
    const int nrow4 = (lane >> 4) * 4;
    #pragma unroll
    for (int i = 0; i < 4; ++i)
        #pragma unroll
        for (int j = 0; j < 4; ++j) {
            int gm = bm + wr + i * 16 + mcol;
            int gn = bn + wc + j * 16 + nrow4;
            ushort4 pk;
            pk.x = f2bf(acc[i][j][0]);
            pk.y = f2bf(acc[i][j][1]);
            pk.z = f2bf(acc[i][j][2]);
            pk.w = f2bf(acc[i][j][3]);
            *(ushort4*)&C[(long)gm * NMID + gn] = pk;
        }
}

// ---- SNU recurrence: Z,Y in [T][B][N] bf16; thread = (b, n-pair) -----------
__global__ void snu_recur(const __hip_bfloat16* __restrict__ Z,
                          const float* __restrict__ bias,
                          __hip_bfloat16* __restrict__ Y) {
    int idx = blockIdx.x * BDIM + threadIdx.x;   // [0, BB*NMID/2)
    int n2 = (idx & (NMID / 2 - 1)) * 2;
    int b  = idx >> 9;
    float2 bv = *(const float2*)(bias + n2);
    float s0 = 0.0f, y0 = 0.0f, s1 = 0.0f, y1 = 0.0f;
    const long base = (long)b * NMID + n2;
    const long stride = (long)BB * NMID;
    for (int t = 0; t < TT; ++t) {
        ushort2 z2 = *(const ushort2*)(Z + base + t * stride);
        float z0 = bf2f(z2.x), z1 = bf2f(z2.y);
        s0 = fmaxf(fmaf(L_TAU * s0, 1.0f - y0, z0), 0.0f);
        y0 = 1.0f / (1.0f + __expf(-(s0 + bv.x)));
        s1 = fmaxf(fmaf(L_TAU * s1, 1.0f - y1, z1), 0.0f);
        y1 = 1.0f / (1.0f + __expf(-(s1 + bv.y)));
        ushort2 o;
        o.x = f2bf(y0);
        o.y = f2bf(y1);
        *(ushort2*)(Y + base + t * stride) = o;
    }
}

// ---- Layer 4 GEMM: Z4[M,10] = Y3[M,1024] * W4[1024,10] ---------------------
__global__ __launch_bounds__(256) void layer4_gemm(const __hip_bfloat16* __restrict__ Y3,
                                                   const float* __restrict__ W4,
                                                   float* __restrict__ Z4) {
    __shared__ float w4t[NOUT][NMID];   // 40 KB
    int tid = threadIdx.x;
    for (int i = tid; i < NOUT * NMID; i += BDIM) {
        int n = i >> 10;
        int k = i & (NMID - 1);
        w4t[n][k] = W4[k * NOUT + n];
    }
    __syncthreads();
    int wave = tid >> 6, lane = tid & 63;
    for (int rr = 0; rr < 16; ++rr) {
        int m = blockIdx.x * 64 + wave * 16 + rr;
        const __hip_bfloat16* yrow = Y3 + (long)m * NMID;
        float yv[16];
        #pragma unroll
        for (int j = 0; j < 16; ++j)
            yv[j] = __bfloat162float(yrow[j * 64 + lane]);
        float res = 0.0f;
        #pragma unroll
        for (int n = 0; n < NOUT; ++n) {
            float a = 0.0f;
            #pragma unroll
            for (int j = 0; j < 16; ++j)
                a = fmaf(yv[j], w4t[n][j * 64 + lane], a);
            #pragma unroll
            for (int off = 32; off; off >>= 1)
                a += __shfl_xor(a, off);
            if (lane == n) res = a;
        }
        if (lane < NOUT) Z4[(long)m * NOUT + lane] = res;
    }
}

// ---- Layer 4 recurrence + m accumulation (Z4 rows are t-major) -------------
__global__ void snu4_recur(const float* __restrict__ Z4, const float* __restrict__ b4,
                           float* __restrict__ m_out) {
    int idx = blockIdx.x * BDIM + threadIdx.x;   // b*10+n
    if (idx >= BB * NOUT) return;
    int n = idx % NOUT;
    float bv = b4[n];
    float s = 0.0f, y = 0.0f, msum = 0.0f;
    for (int t = 0; t < TT; ++t) {
        float z = Z4[(long)t * BB * NOUT + idx];   // coalesced across idx
        s = fmaxf(fmaf(L_TAU * s, 1.0f - y, z), 0.0f);
        y = 1.0f / (1.0f + __expf(-(s + bv)));
        msum += y;
    }
    m_out[idx] = msum;
}

// ---- loss = -mean_b log_softmax(m)[b, y[b]] --------------------------------
__global__ void loss_kernel(const float* __restrict__ m, const int* __restrict__ y,
                            float* __restrict__ out) {
    __shared__ float red[BDIM];
    int b = threadIdx.x;   // 256 threads, 1 block
    float v[NOUT];
    float mx = -1e30f;
    #pragma unroll
    for (int n = 0; n < NOUT; ++n) { v[n] = m[b * NOUT + n]; mx = fmaxf(mx, v[n]); }
    float se = 0.0f;
    #pragma unroll
    for (int n = 0; n < NOUT; ++n) se += __expf(v[n] - mx);
    float lse = mx + __logf(se);
    int lbl = y[b];
    float vy = 0.0f;
    #pragma unroll
    for (int n = 0; n < NOUT; ++n) if (n == lbl) vy = v[n];
    red[b] = -(vy - lse);
    __syncthreads();
    for (int off = 128; off; off >>= 1) {
        if (b < off) red[b] += red[b + off];
        __syncthreads();
    }
    if (b == 0) out[0] = red[0] / (float)BB;
}

extern "C" void kernel_launch(void* const* d_in, const int* in_sizes, int n_in,
                              void* d_out, int out_size, void* d_ws, size_t ws_size,
                              hipStream_t stream) {
    const float* x  = (const float*)d_in[0];
    const int*   y  = (const int*)  d_in[1];
    const float* W1 = (const float*)d_in[2];
    const float* b1 = (const float*)d_in[3];
    const float* W2 = (const float*)d_in[4];
    const float* b2 = (const float*)d_in[5];
    const float* W3 = (const float*)d_in[6];
    const float* b3 = (const float*)d_in[7];
    const float* W4 = (const float*)d_in[8];
    const float* b4 = (const float*)d_in[9];
    float* out = (float*)d_out;

    char* ws = (char*)d_ws;
    size_t off = 0;
    auto alloc = [&](size_t bytes) {
        char* p = ws + off;
        off = (off + bytes + 255) & ~(size_t)255;
        return (void*)p;
    };
    __hip_bfloat16* XB  = (__hip_bfloat16*)alloc((size_t)MM * K1P * 2);
    __hip_bfloat16* W1T = (__hip_bfloat16*)alloc((size_t)NMID * K1P * 2);
    __hip_bfloat16* W2T = (__hip_bfloat16*)alloc((size_t)NMID * NMID * 2);
    __hip_bfloat16* W3T = (__hip_bfloat16*)alloc((size_t)NMID * NMID * 2);
    __hip_bfloat16* Z   = (__hip_bfloat16*)alloc((size_t)MM * NMID * 2);  // [T][B][N]
    __hip_bfloat16* Ya  = (__hip_bfloat16*)alloc((size_t)MM * NMID * 2);
    __hip_bfloat16* Yb  = (__hip_bfloat16*)alloc((size_t)MM * NMID * 2);
    float*          Z4  = (float*)         alloc((size_t)MM * NOUT * 4);

    // prep: convert x (to t-major rows), transpose+convert weights
    convert_x<<<MM, BDIM, 0, stream>>>(x, XB);
    transpose_convert<<<dim3(K1P / 32, NMID / 32), BDIM, 0, stream>>>(W1, W1T, K1, NMID, K1P);
    transpose_convert<<<dim3(NMID / 32, NMID / 32), BDIM, 0, stream>>>(W2, W2T, NMID, NMID, NMID);
    transpose_convert<<<dim3(NMID / 32, NMID / 32), BDIM, 0, stream>>>(W3, W3T, NMID, NMID, NMID);

    const int gblocks = MSTRIPS * NSTRIPS;   // 1600
    const int rblocks = (BB * NMID / 2) / BDIM;   // 512
    // layer 1
    gemm_bt<<<gblocks, BDIM, 0, stream>>>(XB, W1T, Z, K1P);
    snu_recur<<<rblocks, BDIM, 0, stream>>>(Z, b1, Ya);
    // layer 2
    gemm_bt<<<gblocks, BDIM, 0, stream>>>(Ya, W2T, Z, NMID);
    snu_recur<<<rblocks, BDIM, 0, stream>>>(Z, b2, Yb);
    // layer 3 (reuse Ya)
    gemm_bt<<<gblocks, BDIM, 0, stream>>>(Yb, W3T, Z, NMID);
    snu_recur<<<rblocks, BDIM, 0, stream>>>(Z, b3, Ya);
    // layer 4
    layer4_gemm<<<MM / 64, BDIM, 0, stream>>>(Ya, W4, Z4);
    snu4_recur<<<(BB * NOUT + BDIM - 1) / BDIM, BDIM, 0, stream>>>(Z4, b4, out + 1);
    loss_kernel<<<1, BDIM, 0, stream>>>(out + 1, y, out);
}

// Round 4
// 411.312 us; speedup vs baseline: 1.4249x; 1.2116x over previous
//
#include <hip/hip_runtime.h>
#include <hip/hip_bf16.h>

// SNU network: 4 layers, B=256, T=100, N_IN=784, N_MID=1024, N_OUT=10, tau=0.8
// Layer-batched, activations [T][B][N] (m = t*B+b) in fp8 e4m3; GEMMs use
// mfma_scale_f32_16x16x128_f8f6f4 with unit scales (2x bf16 MFMA rate, half
// staging). Z (pre-activation) stays bf16. Recurrences fully coalesced.

#define BDIM 256
#define TT   100
#define BB   256
#define MM   25600       // B*T
#define NMID 1024
#define K1   784
#define K1P  896         // 784 padded to 7*128
#define NOUT 10
#define L_TAU 0.8f

typedef __attribute__((ext_vector_type(4))) int   int4x;
typedef __attribute__((ext_vector_type(8))) int   int8x;
typedef __attribute__((ext_vector_type(4))) float f32x4;

__device__ __forceinline__ void async_copy16(const void* g, void* l) {
    __builtin_amdgcn_global_load_lds(
        (const __attribute__((address_space(1))) unsigned int*)g,
        (__attribute__((address_space(3))) unsigned int*)l,
        16, 0, 0);
}

__device__ __forceinline__ unsigned short f2bf(float f) {
    __hip_bfloat16 h = __float2bfloat16(f);
    return __builtin_bit_cast(unsigned short, h);
}
__device__ __forceinline__ float bf2f(unsigned short u) {
    return __uint_as_float((unsigned)u << 16);
}

// ---- X f32 [B][T][784] -> fp8 [m=t*B+b][896] zero-padded -------------------
__global__ void convert_x(const float* __restrict__ X, unsigned char* __restrict__ XB) {
    int m = blockIdx.x;                  // t*BB + b
    int b = m & (BB - 1);
    int t = m >> 8;
    int th = threadIdx.x;
    if (th >= K1P / 4) return;           // 224 active threads
    int pk = 0;
    if (th < K1 / 4) {                   // 196 threads cover cols 0..783 exactly
        float4 v = *(const float4*)(X + ((long)b * TT + t) * K1 + th * 4);
        pk = __builtin_amdgcn_cvt_pk_fp8_f32(v.x, v.y, 0, false);
        pk = __builtin_amdgcn_cvt_pk_fp8_f32(v.z, v.w, pk, true);
    }
    *(int*)(XB + (long)m * K1P + th * 4) = pk;
}

// ---- W f32 [K,N] -> WT fp8 [N,Kpad], zero-pad k>=K -------------------------
__global__ void transpose_convert(const float* __restrict__ W, unsigned char* __restrict__ WT,
                                  int K, int N, int Kpad) {
    __shared__ float tile[32][33];
    int k0 = blockIdx.x * 32;
    int n0 = blockIdx.y * 32;
    int tx = threadIdx.x & 31, ty = threadIdx.x >> 5;   // 256 threads: ty=0..7
    #pragma unroll
    for (int i = 0; i < 4; ++i) {
        int k = k0 + ty + i * 8;
        tile[ty + i * 8][tx] = (k < K) ? W[(long)k * N + n0 + tx] : 0.0f;
    }
    __syncthreads();
    int nl = threadIdx.x >> 3, kq = threadIdx.x & 7;    // n-local 0..31, k-quad 0..7
    int pk = __builtin_amdgcn_cvt_pk_fp8_f32(tile[kq * 4 + 0][nl], tile[kq * 4 + 1][nl], 0, false);
    pk     = __builtin_amdgcn_cvt_pk_fp8_f32(tile[kq * 4 + 2][nl], tile[kq * 4 + 3][nl], pk, true);
    *(int*)(WT + (long)(n0 + nl) * Kpad + k0 + kq * 4) = pk;
}

// ---- GEMM: C[M,N] = A[M,K] * BT[N,K]^T, fp8 in, bf16 out -------------------
// 128x128 tile, BK=128 bytes, 4 waves of 64x64, 16x16x128 f8f6f4 MFMA with
// unit scales. Swapped operands -> acc reg-dim = n -> packed ushort4 stores.
// Chunk-XOR LDS swizzle (conflict-free b128); XCD-aware block swizzle.
#define BM 128
#define BN 128
#define BKB 128          // K bytes per tile
#define MSTRIPS (MM / BM)        // 200
#define NSTRIPS (NMID / BN)      // 8
__global__ __launch_bounds__(256) void gemm_fp8(
    const unsigned char* __restrict__ A,    // [M,Kp] fp8
    const unsigned char* __restrict__ BT,   // [N,Kp] fp8
    __hip_bfloat16* __restrict__ C,         // [M,N] bf16
    int Kp)
{
    __shared__ unsigned char As[BM * BKB];  // 16 KB; slot c holds global chunk c^(row&7)
    __shared__ unsigned char Bs[BN * BKB];

    const int tid  = threadIdx.x;
    const int wave = tid >> 6;
    const int lane = tid & 63;

    // XCD swizzle: whole M-strips per XCD so all 8 N-blocks share the A strip in L2
    const int l    = blockIdx.x;
    const int xcd  = l & 7;
    const int p    = l >> 3;
    const int bm   = (xcd * (MSTRIPS / 8) + (p >> 3)) * BM;
    const int bn   = (p & 7) * BN;

    const int wr = (wave >> 1) * 64;
    const int wc = (wave & 1) * 64;

    f32x4 acc[4][4] = {};

    // staging: LDS dest lane-linear (tid*16B); global chunk XOR-swizzled by row&7
    const int srow = tid >> 3;
    const int lch  = tid & 7;
    const int gch  = lch ^ (srow & 7);
    const unsigned char* Aptr = A  + (long)(bm + srow) * Kp + gch * 16;
    const unsigned char* Bptr = BT + (long)(bn + srow) * Kp + gch * 16;

    for (int k0 = 0; k0 < Kp; k0 += BKB) {
        #pragma unroll
        for (int i = 0; i < 4; ++i) {
            async_copy16(Aptr + (long)(i * 32) * Kp + k0, &As[(srow + i * 32) * BKB + lch * 16]);
            async_copy16(Bptr + (long)(i * 32) * Kp + k0, &Bs[(srow + i * 32) * BKB + lch * 16]);
        }
        __syncthreads();

        const int mrow = lane & 15;
        const int g    = lane >> 4;          // K-group: k = g*32 .. g*32+31
        int8x af[4], bfr[4];
        #pragma unroll
        for (int i = 0; i < 4; ++i) {
            int row = wr + i * 16 + mrow;
            int r7  = row & 7;
            int4x lo = *(const int4x*)&As[row * BKB + ((2 * g    ) ^ r7) * 16];
            int4x hi = *(const int4x*)&As[row * BKB + ((2 * g + 1) ^ r7) * 16];
            af[i][0] = lo[0]; af[i][1] = lo[1]; af[i][2] = lo[2]; af[i][3] = lo[3];
            af[i][4] = hi[0]; af[i][5] = hi[1]; af[i][6] = hi[2]; af[i][7] = hi[3];
        }
        #pragma unroll
        for (int j = 0; j < 4; ++j) {
            int row = wc + j * 16 + mrow;
            int r7  = row & 7;
            int4x lo = *(const int4x*)&Bs[row * BKB + ((2 * g    ) ^ r7) * 16];
            int4x hi = *(const int4x*)&Bs[row * BKB + ((2 * g + 1) ^ r7) * 16];
            bfr[j][0] = lo[0]; bfr[j][1] = lo[1]; bfr[j][2] = lo[2]; bfr[j][3] = lo[3];
            bfr[j][4] = hi[0]; bfr[j][5] = hi[1]; bfr[j][6] = hi[2]; bfr[j][7] = hi[3];
        }
        #pragma unroll
        for (int i = 0; i < 4; ++i)
            #pragma unroll
            for (int j = 0; j < 4; ++j)
                acc[i][j] = __builtin_amdgcn_mfma_scale_f32_16x16x128_f8f6f4(
                    bfr[j], af[i], acc[i][j],
                    0, 0,            // cbsz=fp8 e4m3, blgp=fp8 e4m3
                    0, 0x7F,         // scale src0 = 2^0
                    0, 0x7F);        // scale src1 = 2^0
        __syncthreads();
    }

    // epilogue: 16x16 C/D layout: lane&15 -> m, (lane>>4)*4+reg -> n (swapped ops)
    const int mcol  = lane & 15;
    const int nrow4 = (lane >> 4) * 4;
    #pragma unroll
    for (int i = 0; i < 4; ++i)
        #pragma unroll
        for (int j = 0; j < 4; ++j) {
            int gm = bm + wr + i * 16 + mcol;
            int gn = bn + wc + j * 16 + nrow4;
            ushort4 pk;
            pk.x = f2bf(acc[i][j][0]);
            pk.y = f2bf(acc[i][j][1]);
            pk.z = f2bf(acc[i][j][2]);
            pk.w = f2bf(acc[i][j][3]);
            *(ushort4*)&C[(long)gm * NMID + gn] = pk;
        }
}

// ---- SNU recurrence: Z bf16 [T][B][N] -> Y fp8 [T][B][N]; thread=(b,n-pair) -
__global__ void snu_recur(const __hip_bfloat16* __restrict__ Z,
                          const float* __restrict__ bias,
                          unsigned char* __restrict__ Y) {
    int idx = blockIdx.x * BDIM + threadIdx.x;   // [0, BB*NMID/2)
    int n2 = (idx & (NMID / 2 - 1)) * 2;
    int b  = idx >> 9;
    float2 bv = *(const float2*)(bias + n2);
    float s0 = 0.0f, y0 = 0.0f, s1 = 0.0f, y1 = 0.0f;
    const long base = (long)b * NMID + n2;
    const long stride = (long)BB * NMID;
    for (int t = 0; t < TT; ++t) {
        ushort2 z2 = *(const ushort2*)(Z + base + t * stride);
        float z0 = bf2f(z2.x), z1 = bf2f(z2.y);
        s0 = fmaxf(fmaf(L_TAU * s0, 1.0f - y0, z0), 0.0f);
        y0 = 1.0f / (1.0f + __expf(-(s0 + bv.x)));
        s1 = fmaxf(fmaf(L_TAU * s1, 1.0f - y1, z1), 0.0f);
        y1 = 1.0f / (1.0f + __expf(-(s1 + bv.y)));
        int pk = __builtin_amdgcn_cvt_pk_fp8_f32(y0, y1, 0, false);
        *(unsigned short*)(Y + base + t * stride) = (unsigned short)pk;
    }
}

// ---- Layer 4 GEMM: Z4[M,10] = Y3[M,1024](fp8) * W4[1024,10](f32) -----------
// 1600 blocks x 16 rows (4 rows/wave); W4 staged [n][k] in LDS, k=j*64+lane
// access is lane-stride-1 -> conflict-free.
__global__ __launch_bounds__(256) void layer4_gemm(const unsigned char* __restrict__ Y3,
                                                   const float* __restrict__ W4,
                                                   float* __restrict__ Z4) {
    __shared__ float w4t[NOUT][NMID];   // 40 KB
    int tid = threadIdx.x;
    for (int i = tid; i < NOUT * NMID; i += BDIM) {
        int n = i >> 10;
        int k = i & (NMID - 1);
        w4t[n][k] = W4[k * NOUT + n];
    }
    __syncthreads();
    int wave = tid >> 6, lane = tid & 63;
    #pragma unroll
    for (int rr = 0; rr < 4; ++rr) {
        int m = blockIdx.x * 16 + wave * 4 + rr;
        const unsigned char* yrow = Y3 + (long)m * NMID;
        float yv[16];
        #pragma unroll
        for (int j = 0; j < 16; ++j)
            yv[j] = __builtin_amdgcn_cvt_f32_fp8((int)yrow[j * 64 + lane], 0);
        float res = 0.0f;
        #pragma unroll
        for (int n = 0; n < NOUT; ++n) {
            float a = 0.0f;
            #pragma unroll
            for (int j = 0; j < 16; ++j)
                a = fmaf(yv[j], w4t[n][j * 64 + lane], a);
            #pragma unroll
            for (int off = 32; off; off >>= 1)
                a += __shfl_xor(a, off);
            if (lane == n) res = a;
        }
        if (lane < NOUT) Z4[(long)m * NOUT + lane] = res;
    }
}

// ---- Layer 4 recurrence + m accumulation (Z4 rows t-major) -----------------
__global__ void snu4_recur(const float* __restrict__ Z4, const float* __restrict__ b4,
                           float* __restrict__ m_out) {
    int idx = blockIdx.x * BDIM + threadIdx.x;   // b*10+n
    if (idx >= BB * NOUT) return;
    int n = idx % NOUT;
    float bv = b4[n];
    float s = 0.0f, y = 0.0f, msum = 0.0f;
    for (int t = 0; t < TT; ++t) {
        float z = Z4[(long)t * BB * NOUT + idx];   // coalesced across idx
        s = fmaxf(fmaf(L_TAU * s, 1.0f - y, z), 0.0f);
        y = 1.0f / (1.0f + __expf(-(s + bv)));
        msum += y;
    }
    m_out[idx] = msum;
}

// ---- loss = -mean_b log_softmax(m)[b, y[b]] --------------------------------
__global__ void loss_kernel(const float* __restrict__ m, const int* __restrict__ y,
                            float* __restrict__ out) {
    __shared__ float red[BDIM];
    int b = threadIdx.x;   // 256 threads, 1 block
    float v[NOUT];
    float mx = -1e30f;
    #pragma unroll
    for (int n = 0; n < NOUT; ++n) { v[n] = m[b * NOUT + n]; mx = fmaxf(mx, v[n]); }
    float se = 0.0f;
    #pragma unroll
    for (int n = 0; n < NOUT; ++n) se += __expf(v[n] - mx);
    float lse = mx + __logf(se);
    int lbl = y[b];
    float vy = 0.0f;
    #pragma unroll
    for (int n = 0; n < NOUT; ++n) if (n == lbl) vy = v[n];
    red[b] = -(vy - lse);
    __syncthreads();
    for (int off = 128; off; off >>= 1) {
        if (b < off) red[b] += red[b + off];
        __syncthreads();
    }
    if (b == 0) out[0] = red[0] / (float)BB;
}

extern "C" void kernel_launch(void* const* d_in, const int* in_sizes, int n_in,
                              void* d_out, int out_size, void* d_ws, size_t ws_size,
                              hipStream_t stream) {
    const float* x  = (const float*)d_in[0];
    const int*   y  = (const int*)  d_in[1];
    const float* W1 = (const float*)d_in[2];
    const float* b1 = (const float*)d_in[3];
    const float* W2 = (const float*)d_in[4];
    const float* b2 = (const float*)d_in[5];
    const float* W3 = (const float*)d_in[6];
    const float* b3 = (const float*)d_in[7];
    const float* W4 = (const float*)d_in[8];
    const float* b4 = (const float*)d_in[9];
    float* out = (float*)d_out;

    char* ws = (char*)d_ws;
    size_t off = 0;
    auto alloc = [&](size_t bytes) {
        char* p = ws + off;
        off = (off + bytes + 255) & ~(size_t)255;
        return (void*)p;
    };
    unsigned char*  XB  = (unsigned char*) alloc((size_t)MM * K1P);
    unsigned char*  W1T = (unsigned char*) alloc((size_t)NMID * K1P);
    unsigned char*  W2T = (unsigned char*) alloc((size_t)NMID * NMID);
    unsigned char*  W3T = (unsigned char*) alloc((size_t)NMID * NMID);
    __hip_bfloat16* Z   = (__hip_bfloat16*)alloc((size_t)MM * NMID * 2);  // [T][B][N]
    unsigned char*  Ya  = (unsigned char*) alloc((size_t)MM * NMID);
    unsigned char*  Yb  = (unsigned char*) alloc((size_t)MM * NMID);
    float*          Z4  = (float*)         alloc((size_t)MM * NOUT * 4);

    // prep: convert x (t-major rows) to fp8, transpose+convert weights to fp8
    convert_x<<<MM, BDIM, 0, stream>>>(x, XB);
    transpose_convert<<<dim3(K1P / 32, NMID / 32), BDIM, 0, stream>>>(W1, W1T, K1, NMID, K1P);
    transpose_convert<<<dim3(NMID / 32, NMID / 32), BDIM, 0, stream>>>(W2, W2T, NMID, NMID, NMID);
    transpose_convert<<<dim3(NMID / 32, NMID / 32), BDIM, 0, stream>>>(W3, W3T, NMID, NMID, NMID);

    const int gblocks = MSTRIPS * NSTRIPS;        // 1600
    const int rblocks = (BB * NMID / 2) / BDIM;   // 512
    // layer 1
    gemm_fp8<<<gblocks, BDIM, 0, stream>>>(XB, W1T, Z, K1P);
    snu_recur<<<rblocks, BDIM, 0, stream>>>(Z, b1, Ya);
    // layer 2
    gemm_fp8<<<gblocks, BDIM, 0, stream>>>(Ya, W2T, Z, NMID);
    snu_recur<<<rblocks, BDIM, 0, stream>>>(Z, b2, Yb);
    // layer 3 (reuse Ya)
    gemm_fp8<<<gblocks, BDIM, 0, stream>>>(Yb, W3T, Z, NMID);
    snu_recur<<<rblocks, BDIM, 0, stream>>>(Z, b3, Ya);
    // layer 4
    layer4_gemm<<<MM / 16, BDIM, 0, stream>>>(Ya, W4, Z4);
    snu4_recur<<<(BB * NOUT + BDIM - 1) / BDIM, BDIM, 0, stream>>>(Z4, b4, out + 1);
    loss_kernel<<<1, BDIM, 0, stream>>>(out + 1, y, out);
}

// Round 5
// 394.162 us; speedup vs baseline: 1.4869x; 1.0435x over previous
//
#include <hip/hip_runtime.h>
#include <hip/hip_bf16.h>

// SNU network: 4 layers, B=256, T=100, N_IN=784, N_MID=1024, N_OUT=10, tau=0.8
// Layer-batched, activations [T][B][N] (m = t*B+b) in fp8 e4m3; GEMMs use
// mfma_scale_f32_16x16x128_f8f6f4 with unit scales (2x bf16 MFMA rate, half
// staging). Z (pre-activation) stays bf16. Recurrences fully coalesced.
// Layer 4 (N=10->16) is an MFMA kernel too.

#define BDIM 256
#define TT   100
#define BB   256
#define MM   25600       // B*T
#define NMID 1024
#define K1   784
#define K1P  896         // 784 padded to 7*128
#define NOUT 10
#define N4P  16          // layer-4 N padded
#define L_TAU 0.8f

typedef __attribute__((ext_vector_type(4))) int   int4x;
typedef __attribute__((ext_vector_type(8))) int   int8x;
typedef __attribute__((ext_vector_type(4))) float f32x4;

__device__ __forceinline__ void async_copy16(const void* g, void* l) {
    __builtin_amdgcn_global_load_lds(
        (const __attribute__((address_space(1))) unsigned int*)g,
        (__attribute__((address_space(3))) unsigned int*)l,
        16, 0, 0);
}

__device__ __forceinline__ unsigned short f2bf(float f) {
    __hip_bfloat16 h = __float2bfloat16(f);
    return __builtin_bit_cast(unsigned short, h);
}
__device__ __forceinline__ float bf2f(unsigned short u) {
    return __uint_as_float((unsigned)u << 16);
}

// ---- X f32 [B][T][784] -> fp8 [m=t*B+b][896] zero-padded -------------------
__global__ void convert_x(const float* __restrict__ X, unsigned char* __restrict__ XB) {
    int m = blockIdx.x;                  // t*BB + b
    int b = m & (BB - 1);
    int t = m >> 8;
    int th = threadIdx.x;
    if (th >= K1P / 4) return;           // 224 active threads
    int pk = 0;
    if (th < K1 / 4) {                   // 196 threads cover cols 0..783 exactly
        float4 v = *(const float4*)(X + ((long)b * TT + t) * K1 + th * 4);
        pk = __builtin_amdgcn_cvt_pk_fp8_f32(v.x, v.y, 0, false);
        pk = __builtin_amdgcn_cvt_pk_fp8_f32(v.z, v.w, pk, true);
    }
    *(int*)(XB + (long)m * K1P + th * 4) = pk;
}

// ---- W f32 [K,N] -> WT fp8 [N,Kpad], zero-pad k>=K -------------------------
__global__ void transpose_convert(const float* __restrict__ W, unsigned char* __restrict__ WT,
                                  int K, int N, int Kpad) {
    __shared__ float tile[32][33];
    int k0 = blockIdx.x * 32;
    int n0 = blockIdx.y * 32;
    int tx = threadIdx.x & 31, ty = threadIdx.x >> 5;   // 256 threads: ty=0..7
    #pragma unroll
    for (int i = 0; i < 4; ++i) {
        int k = k0 + ty + i * 8;
        tile[ty + i * 8][tx] = (k < K) ? W[(long)k * N + n0 + tx] : 0.0f;
    }
    __syncthreads();
    int nl = threadIdx.x >> 3, kq = threadIdx.x & 7;    // n-local 0..31, k-quad 0..7
    int pk = __builtin_amdgcn_cvt_pk_fp8_f32(tile[kq * 4 + 0][nl], tile[kq * 4 + 1][nl], 0, false);
    pk     = __builtin_amdgcn_cvt_pk_fp8_f32(tile[kq * 4 + 2][nl], tile[kq * 4 + 3][nl], pk, true);
    *(int*)(WT + (long)(n0 + nl) * Kpad + k0 + kq * 4) = pk;
}

// ---- W4 f32 [1024,10] -> fp8 [16][1024], zero-pad n>=10 --------------------
__global__ void convert_w4(const float* __restrict__ W4, unsigned char* __restrict__ W4T) {
    int tid = blockIdx.x * BDIM + threadIdx.x;   // n*256 + k4, 4096 total
    int n = tid >> 8;
    int k4 = (tid & 255) * 4;
    float v0 = 0, v1 = 0, v2 = 0, v3 = 0;
    if (n < NOUT) {
        v0 = W4[(k4 + 0) * NOUT + n];
        v1 = W4[(k4 + 1) * NOUT + n];
        v2 = W4[(k4 + 2) * NOUT + n];
        v3 = W4[(k4 + 3) * NOUT + n];
    }
    int pk = __builtin_amdgcn_cvt_pk_fp8_f32(v0, v1, 0, false);
    pk     = __builtin_amdgcn_cvt_pk_fp8_f32(v2, v3, pk, true);
    *(int*)(W4T + (long)n * NMID + k4) = pk;
}

// ---- GEMM: C[M,N] = A[M,K] * BT[N,K]^T, fp8 in, bf16 out -------------------
// 128x128 tile, BK=128 bytes, 4 waves of 64x64, 16x16x128 f8f6f4 MFMA with
// unit scales. Swapped operands -> acc reg-dim = n -> packed ushort4 stores.
// Chunk-XOR LDS swizzle (conflict-free b128); XCD-aware block swizzle.
#define BM 128
#define BN 128
#define BKB 128          // K bytes per tile
#define MSTRIPS (MM / BM)        // 200
#define NSTRIPS (NMID / BN)      // 8
__global__ __launch_bounds__(256) void gemm_fp8(
    const unsigned char* __restrict__ A,    // [M,Kp] fp8
    const unsigned char* __restrict__ BT,   // [N,Kp] fp8
    __hip_bfloat16* __restrict__ C,         // [M,N] bf16
    int Kp)
{
    __shared__ unsigned char As[BM * BKB];  // 16 KB; slot c holds global chunk c^(row&7)
    __shared__ unsigned char Bs[BN * BKB];

    const int tid  = threadIdx.x;
    const int wave = tid >> 6;
    const int lane = tid & 63;

    // XCD swizzle: whole M-strips per XCD so all 8 N-blocks share the A strip in L2
    const int l    = blockIdx.x;
    const int xcd  = l & 7;
    const int p    = l >> 3;
    const int bm   = (xcd * (MSTRIPS / 8) + (p >> 3)) * BM;
    const int bn   = (p & 7) * BN;

    const int wr = (wave >> 1) * 64;
    const int wc = (wave & 1) * 64;

    f32x4 acc[4][4] = {};

    // staging: LDS dest lane-linear (tid*16B); global chunk XOR-swizzled by row&7
    const int srow = tid >> 3;
    const int lch  = tid & 7;
    const int gch  = lch ^ (srow & 7);
    const unsigned char* Aptr = A  + (long)(bm + srow) * Kp + gch * 16;
    const unsigned char* Bptr = BT + (long)(bn + srow) * Kp + gch * 16;

    for (int k0 = 0; k0 < Kp; k0 += BKB) {
        #pragma unroll
        for (int i = 0; i < 4; ++i) {
            async_copy16(Aptr + (long)(i * 32) * Kp + k0, &As[(srow + i * 32) * BKB + lch * 16]);
            async_copy16(Bptr + (long)(i * 32) * Kp + k0, &Bs[(srow + i * 32) * BKB + lch * 16]);
        }
        __syncthreads();

        const int mrow = lane & 15;
        const int g    = lane >> 4;          // K-group: k = g*32 .. g*32+31
        int8x af[4], bfr[4];
        #pragma unroll
        for (int i = 0; i < 4; ++i) {
            int row = wr + i * 16 + mrow;
            int r7  = row & 7;
            int4x lo = *(const int4x*)&As[row * BKB + ((2 * g    ) ^ r7) * 16];
            int4x hi = *(const int4x*)&As[row * BKB + ((2 * g + 1) ^ r7) * 16];
            af[i][0] = lo[0]; af[i][1] = lo[1]; af[i][2] = lo[2]; af[i][3] = lo[3];
            af[i][4] = hi[0]; af[i][5] = hi[1]; af[i][6] = hi[2]; af[i][7] = hi[3];
        }
        #pragma unroll
        for (int j = 0; j < 4; ++j) {
            int row = wc + j * 16 + mrow;
            int r7  = row & 7;
            int4x lo = *(const int4x*)&Bs[row * BKB + ((2 * g    ) ^ r7) * 16];
            int4x hi = *(const int4x*)&Bs[row * BKB + ((2 * g + 1) ^ r7) * 16];
            bfr[j][0] = lo[0]; bfr[j][1] = lo[1]; bfr[j][2] = lo[2]; bfr[j][3] = lo[3];
            bfr[j][4] = hi[0]; bfr[j][5] = hi[1]; bfr[j][6] = hi[2]; bfr[j][7] = hi[3];
        }
        #pragma unroll
        for (int i = 0; i < 4; ++i)
            #pragma unroll
            for (int j = 0; j < 4; ++j)
                acc[i][j] = __builtin_amdgcn_mfma_scale_f32_16x16x128_f8f6f4(
                    bfr[j], af[i], acc[i][j],
                    0, 0,            // cbsz=fp8 e4m3, blgp=fp8 e4m3
                    0, 0x7F,         // scale src0 = 2^0
                    0, 0x7F);        // scale src1 = 2^0
        __syncthreads();
    }

    // epilogue: 16x16 C/D layout: lane&15 -> m, (lane>>4)*4+reg -> n (swapped ops)
    const int mcol  = lane & 15;
    const int nrow4 = (lane >> 4) * 4;
    #pragma unroll
    for (int i = 0; i < 4; ++i)
        #pragma unroll
        for (int j = 0; j < 4; ++j) {
            int gm = bm + wr + i * 16 + mcol;
            int gn = bn + wc + j * 16 + nrow4;
            ushort4 pk;
            pk.x = f2bf(acc[i][j][0]);
            pk.y = f2bf(acc[i][j][1]);
            pk.z = f2bf(acc[i][j][2]);
            pk.w = f2bf(acc[i][j][3]);
            *(ushort4*)&C[(long)gm * NMID + gn] = pk;
        }
}

// ---- SNU recurrence: Z bf16 [T][B][N] -> Y fp8 [T][B][N]; thread=(b,n-pair) -
__global__ void snu_recur(const __hip_bfloat16* __restrict__ Z,
                          const float* __restrict__ bias,
                          unsigned char* __restrict__ Y) {
    int idx = blockIdx.x * BDIM + threadIdx.x;   // [0, BB*NMID/2)
    int n2 = (idx & (NMID / 2 - 1)) * 2;
    int b  = idx >> 9;
    float2 bv = *(const float2*)(bias + n2);
    float s0 = 0.0f, y0 = 0.0f, s1 = 0.0f, y1 = 0.0f;
    const long base = (long)b * NMID + n2;
    const long stride = (long)BB * NMID;
    for (int t = 0; t < TT; ++t) {
        ushort2 z2 = *(const ushort2*)(Z + base + t * stride);
        float z0 = bf2f(z2.x), z1 = bf2f(z2.y);
        s0 = fmaxf(fmaf(L_TAU * s0, 1.0f - y0, z0), 0.0f);
        y0 = 1.0f / (1.0f + __expf(-(s0 + bv.x)));
        s1 = fmaxf(fmaf(L_TAU * s1, 1.0f - y1, z1), 0.0f);
        y1 = 1.0f / (1.0f + __expf(-(s1 + bv.y)));
        int pk = __builtin_amdgcn_cvt_pk_fp8_f32(y0, y1, 0, false);
        *(unsigned short*)(Y + base + t * stride) = (unsigned short)pk;
    }
}

// ---- Layer 4 GEMM: Z4[M,16] = Y3[M,1024](fp8) * W4T[16,1024]^T (fp8) -------
// 400 blocks x 64 rows; W4 in LDS (stride 1040 B -> free 2-way aliasing);
// A-tile staged per K-step with XOR-chunk swizzle; 1 MFMA/wave/K-step.
#define L4_BM 64
#define W4STR 1040
__global__ __launch_bounds__(256) void layer4_gemm(const unsigned char* __restrict__ Y3,
                                                   const unsigned char* __restrict__ W4T,
                                                   float* __restrict__ Z4) {
    __shared__ unsigned char As[L4_BM * BKB];     // 8 KB
    __shared__ unsigned char W4s[N4P * W4STR];    // 16.25 KB
    const int tid  = threadIdx.x;
    const int wave = tid >> 6;
    const int lane = tid & 63;
    const int bm   = blockIdx.x * L4_BM;

    // stage W4T -> LDS; per instr: n uniform per wave, dest = base + lane*16
    #pragma unroll
    for (int j = 0; j < 4; ++j) {
        int n = j * 4 + wave;
        async_copy16(W4T + (long)n * NMID + lane * 16, &W4s[n * W4STR + lane * 16]);
    }

    const int srow = tid >> 3;           // 0..31
    const int lch  = tid & 7;
    const int gch  = lch ^ (srow & 7);
    const unsigned char* Aptr = Y3 + (long)(bm + srow) * NMID + gch * 16;

    f32x4 acc = {};
    const int mrow = lane & 15;
    const int g    = lane >> 4;

    for (int k0 = 0; k0 < NMID; k0 += BKB) {
        #pragma unroll
        for (int i = 0; i < 2; ++i)
            async_copy16(Aptr + (long)(i * 32) * NMID + k0, &As[(srow + i * 32) * BKB + lch * 16]);
        __syncthreads();   // drains W4 staging too (first iter)

        int row = wave * 16 + mrow;
        int r7  = row & 7;
        int4x lo = *(const int4x*)&As[row * BKB + ((2 * g    ) ^ r7) * 16];
        int4x hi = *(const int4x*)&As[row * BKB + ((2 * g + 1) ^ r7) * 16];
        int8x af;
        af[0] = lo[0]; af[1] = lo[1]; af[2] = lo[2]; af[3] = lo[3];
        af[4] = hi[0]; af[5] = hi[1]; af[6] = hi[2]; af[7] = hi[3];
        int4x wlo = *(const int4x*)&W4s[mrow * W4STR + k0 + g * 32];
        int4x whi = *(const int4x*)&W4s[mrow * W4STR + k0 + g * 32 + 16];
        int8x bf;
        bf[0] = wlo[0]; bf[1] = wlo[1]; bf[2] = wlo[2]; bf[3] = wlo[3];
        bf[4] = whi[0]; bf[5] = whi[1]; bf[6] = whi[2]; bf[7] = whi[3];
        acc = __builtin_amdgcn_mfma_scale_f32_16x16x128_f8f6f4(
            bf, af, acc, 0, 0, 0, 0x7F, 0, 0x7F);
        __syncthreads();
    }

    // C/D: lane&15 -> m, (lane>>4)*4+reg -> n; contiguous float4 store
    int gm = bm + wave * 16 + mrow;
    *(f32x4*)&Z4[(long)gm * N4P + g * 4] = acc;
}

// ---- Layer 4 recurrence + m accumulation (Z4 [T*B][16] f32) ----------------
__global__ void snu4_recur(const float* __restrict__ Z4, const float* __restrict__ b4,
                           float* __restrict__ m_out) {
    int idx = blockIdx.x * BDIM + threadIdx.x;   // b*16+n, 4096 total
    int n = idx & 15;
    int b = idx >> 4;
    if (n >= NOUT) return;
    float bv = b4[n];
    float s = 0.0f, y = 0.0f, msum = 0.0f;
    for (int t = 0; t < TT; ++t) {
        float z = Z4[((long)t * BB + b) * N4P + n];   // coalesced across idx
        s = fmaxf(fmaf(L_TAU * s, 1.0f - y, z), 0.0f);
        y = 1.0f / (1.0f + __expf(-(s + bv)));
        msum += y;
    }
    m_out[b * NOUT + n] = msum;
}

// ---- loss = -mean_b log_softmax(m)[b, y[b]] --------------------------------
__global__ void loss_kernel(const float* __restrict__ m, const int* __restrict__ y,
                            float* __restrict__ out) {
    __shared__ float red[BDIM];
    int b = threadIdx.x;   // 256 threads, 1 block
    float v[NOUT];
    float mx = -1e30f;
    #pragma unroll
    for (int n = 0; n < NOUT; ++n) { v[n] = m[b * NOUT + n]; mx = fmaxf(mx, v[n]); }
    float se = 0.0f;
    #pragma unroll
    for (int n = 0; n < NOUT; ++n) se += __expf(v[n] - mx);
    float lse = mx + __logf(se);
    int lbl = y[b];
    float vy = 0.0f;
    #pragma unroll
    for (int n = 0; n < NOUT; ++n) if (n == lbl) vy = v[n];
    red[b] = -(vy - lse);
    __syncthreads();
    for (int off = 128; off; off >>= 1) {
        if (b < off) red[b] += red[b + off];
        __syncthreads();
    }
    if (b == 0) out[0] = red[0] / (float)BB;
}

extern "C" void kernel_launch(void* const* d_in, const int* in_sizes, int n_in,
                              void* d_out, int out_size, void* d_ws, size_t ws_size,
                              hipStream_t stream) {
    const float* x  = (const float*)d_in[0];
    const int*   y  = (const int*)  d_in[1];
    const float* W1 = (const float*)d_in[2];
    const float* b1 = (const float*)d_in[3];
    const float* W2 = (const float*)d_in[4];
    const float* b2 = (const float*)d_in[5];
    const float* W3 = (const float*)d_in[6];
    const float* b3 = (const float*)d_in[7];
    const float* W4 = (const float*)d_in[8];
    const float* b4 = (const float*)d_in[9];
    float* out = (float*)d_out;

    char* ws = (char*)d_ws;
    size_t off = 0;
    auto alloc = [&](size_t bytes) {
        char* p = ws + off;
        off = (off + bytes + 255) & ~(size_t)255;
        return (void*)p;
    };
    unsigned char*  XB  = (unsigned char*) alloc((size_t)MM * K1P);
    unsigned char*  W1T = (unsigned char*) alloc((size_t)NMID * K1P);
    unsigned char*  W2T = (unsigned char*) alloc((size_t)NMID * NMID);
    unsigned char*  W3T = (unsigned char*) alloc((size_t)NMID * NMID);
    unsigned char*  W4T = (unsigned char*) alloc((size_t)N4P * NMID);
    __hip_bfloat16* Z   = (__hip_bfloat16*)alloc((size_t)MM * NMID * 2);  // [T][B][N]
    unsigned char*  Ya  = (unsigned char*) alloc((size_t)MM * NMID);
    unsigned char*  Yb  = (unsigned char*) alloc((size_t)MM * NMID);
    float*          Z4  = (float*)         alloc((size_t)MM * N4P * 4);

    // prep: convert x (t-major rows) to fp8, transpose+convert weights to fp8
    convert_x<<<MM, BDIM, 0, stream>>>(x, XB);
    transpose_convert<<<dim3(K1P / 32, NMID / 32), BDIM, 0, stream>>>(W1, W1T, K1, NMID, K1P);
    transpose_convert<<<dim3(NMID / 32, NMID / 32), BDIM, 0, stream>>>(W2, W2T, NMID, NMID, NMID);
    transpose_convert<<<dim3(NMID / 32, NMID / 32), BDIM, 0, stream>>>(W3, W3T, NMID, NMID, NMID);
    convert_w4<<<N4P * NMID / 4 / BDIM, BDIM, 0, stream>>>(W4, W4T);

    const int gblocks = MSTRIPS * NSTRIPS;        // 1600
    const int rblocks = (BB * NMID / 2) / BDIM;   // 512
    // layer 1
    gemm_fp8<<<gblocks, BDIM, 0, stream>>>(XB, W1T, Z, K1P);
    snu_recur<<<rblocks, BDIM, 0, stream>>>(Z, b1, Ya);
    // layer 2
    gemm_fp8<<<gblocks, BDIM, 0, stream>>>(Ya, W2T, Z, NMID);
    snu_recur<<<rblocks, BDIM, 0, stream>>>(Z, b2, Yb);
    // layer 3 (reuse Ya)
    gemm_fp8<<<gblocks, BDIM, 0, stream>>>(Yb, W3T, Z, NMID);
    snu_recur<<<rblocks, BDIM, 0, stream>>>(Z, b3, Ya);
    // layer 4
    layer4_gemm<<<MM / L4_BM, BDIM, 0, stream>>>(Ya, W4T, Z4);
    snu4_recur<<<(BB * N4P) / BDIM, BDIM, 0, stream>>>(Z4, b4, out + 1);
    loss_kernel<<<1, BDIM, 0, stream>>>(out + 1, y, out);
}